// Round 9
// baseline (14.765 us; speedup 1.0000x reference)
//
#include <hip/hip_runtime.h>
#include <math.h>

// Gauss2DEffect: per-pixel-sigma horizontal Gaussian blur, f32.
// x: [1,3,1024,1024], sigma: [1,1,1024,1024], out: [1,3,1024,1024]
//
// Round 9: occupancy-first done right. Target VGPR <= 64 (the 8-waves/SIMD
// cliff, m69) with NATURAL allocation — no launch_bounds min-waves cap
// (r4/r6: caps force spills). Per-thread state cut to ~60 regs:
//  - PP=2: window v[24], weights wt[2][10]=20.
//  - exp2-direct weights: wi = exp2(c * i^2), c = -log2e/(2s^2). No
//    recurrence state (q,q2,wp,tq gone), no serial dependency chain.
//  - 12 float2 loads per channel (8B aligned, w0 even) off ONE base
//    pointer, offsets fold into load immediates.
//  - w0 = (2*tid + 12) & 1023 rotation: edge segments (tid 501..511) all
//    land in the last wave per row; waves 0..6 take a uniform execz skip.

#define HH 1024
#define WW 1024
#define CC 3
#define KK 10
#define PP 2

__global__ __launch_bounds__(256) void gauss1d_kernel(
    const float* __restrict__ x,
    const float* __restrict__ sigma,
    float* __restrict__ out)
{
    const int t   = blockIdx.x * blockDim.x + threadIdx.x;
    const int row = t >> 9;                      // 512 segments per row
    const int tid = t & 511;
    const int w0  = (tid * PP + 12) & (WW - 1);  // rotated mapping, even
    const int p0  = row * WW + w0;

    // ---- per-pixel constants ----
    const float2 sg = *reinterpret_cast<const float2*>(sigma + p0);
    float c2v[PP], hsv[PP];
    #pragma unroll
    for (int p = 0; p < PP; ++p) {
        const float sig = (p == 0) ? sg.x : sg.y;
        const float inv2s2 = __builtin_amdgcn_rcpf(2.0f * sig * sig);
        c2v[p] = -1.44269504f * inv2s2;          // -log2e / (2s^2)
        hsv[p] = ceilf(2.0f * sig);              // half_step gate
    }

    // ---- weights: wi = exp2(c * i^2), gated; independent per tap ----
    float wt[PP][KK];
    float invn[PP];
    #pragma unroll
    for (int p = 0; p < PP; ++p) {
        float wsum = 0.0f;
        #pragma unroll
        for (int i = 1; i <= KK; ++i) {
            float wi = exp2f(c2v[p] * (float)(i * i));
            wi = ((float)i <= hsv[p]) ? wi : 0.0f;
            wt[p][i - 1] = wi;
            wsum += wi;
        }
        invn[p] = __builtin_amdgcn_rcpf(fmaf(2.0f, wsum, 1.0f));  // norm >= 1
    }

    const int  base     = w0 - 12;               // window start col (even)
    const bool interior = (w0 >= 12) && (w0 <= WW - 12);

    #pragma unroll
    for (int c = 0; c < CC; ++c) {
        const float* __restrict__ rc = x + c * (HH * WW) + row * WW;
        float v[2 * KK + PP + 2];                // 24 cols [w0-12, w0+11]
        if (interior) {                          // waves 0..6: uniform skip
            const float* __restrict__ bp = rc + base;    // 8B aligned
            #pragma unroll
            for (int k = 0; k < 12; ++k) {
                const float2 lv = *reinterpret_cast<const float2*>(bp + 2 * k);
                v[2 * k]     = lv.x;
                v[2 * k + 1] = lv.y;
            }
        } else {                                 // last wave per row only
            #pragma unroll
            for (int k = 0; k < 12; ++k) {
                const int bk = base + 2 * k;     // even
                int bkc = bk < 0 ? 0 : bk;
                bkc = bkc > (WW - 2) ? (WW - 2) : bkc;
                float2 lv = *reinterpret_cast<const float2*>(rc + bkc);
                // bk even -> a pair is never partially OOB.
                if (k < 6)  lv.y = (bk < 0)        ? lv.x : lv.y;  // left clamp
                if (k > 6)  lv.x = (bk > (WW - 2)) ? lv.y : lv.x;  // right clamp
                v[2 * k]     = lv.x;
                v[2 * k + 1] = lv.y;
            }
        }

        float a0 = v[12];                        // center tap, weight == 1
        float a1 = v[13];
        #pragma unroll
        for (int i = 1; i <= KK; ++i) {
            a0 += wt[0][i - 1] * (v[12 - i] + v[12 + i]);
            a1 += wt[1][i - 1] * (v[13 - i] + v[13 + i]);
        }
        const float2 res = {a0 * invn[0], a1 * invn[1]};
        *reinterpret_cast<float2*>(out + c * (HH * WW) + p0) = res;
    }
}

extern "C" void kernel_launch(void* const* d_in, const int* in_sizes, int n_in,
                              void* d_out, int out_size, void* d_ws, size_t ws_size,
                              hipStream_t stream) {
    const float* x = (const float*)d_in[0];
    const float* sigma = (const float*)d_in[1];
    float* out = (float*)d_out;

    const int n_threads = (HH * WW) / PP;   // 524288
    const int block = 256;
    const int grid = n_threads / block;     // 2048
    gauss1d_kernel<<<grid, block, 0, stream>>>(x, sigma, out);
}